// Round 1
// baseline (1312.649 us; speedup 1.0000x reference)
//
#include <hip/hip_runtime.h>
#include <hip/hip_bf16.h>

#define LEAKY 0.2f
#define EPS_GN 1e-5f

// ---------------- CSR build ----------------

__global__ void zero_int_kernel(int* __restrict__ p, int n) {
    int i = blockIdx.x * blockDim.x + threadIdx.x;
    if (i < n) p[i] = 0;
}

__global__ void hist_kernel(const int* __restrict__ dst, int* __restrict__ deg, int E_, int Etot_) {
    int i = blockIdx.x * blockDim.x + threadIdx.x;
    if (i >= Etot_) return;
    int d = (i < E_) ? dst[i] : (i - E_);
    atomicAdd(&deg[d], 1);
}

__global__ void scan1_kernel(const int* __restrict__ deg, int* __restrict__ bsum, int nN) {
    __shared__ int sd[256];
    int i = blockIdx.x * 256 + threadIdx.x;
    sd[threadIdx.x] = (i < nN) ? deg[i] : 0;
    __syncthreads();
    for (int off = 128; off > 0; off >>= 1) {
        if (threadIdx.x < off) sd[threadIdx.x] += sd[threadIdx.x + off];
        __syncthreads();
    }
    if (threadIdx.x == 0) bsum[blockIdx.x] = sd[0];
}

__global__ void scan2_kernel(const int* __restrict__ bsum, int* __restrict__ bofs, int nb,
                             int* __restrict__ rowstart, int nN) {
    if (threadIdx.x == 0 && blockIdx.x == 0) {
        int run = 0;
        for (int i = 0; i < nb; ++i) { bofs[i] = run; run += bsum[i]; }
        rowstart[nN] = run;
    }
}

__global__ void scan3_kernel(const int* __restrict__ deg, const int* __restrict__ bofs,
                             int* __restrict__ rowstart, int nN) {
    __shared__ int sd[256];
    int i = blockIdx.x * 256 + threadIdx.x;
    int v = (i < nN) ? deg[i] : 0;
    sd[threadIdx.x] = v;
    __syncthreads();
    for (int off = 1; off < 256; off <<= 1) {
        int t = (threadIdx.x >= off) ? sd[threadIdx.x - off] : 0;
        __syncthreads();
        sd[threadIdx.x] += t;
        __syncthreads();
    }
    if (i < nN) rowstart[i] = bofs[blockIdx.x] + sd[threadIdx.x] - v;
}

__global__ void fill_kernel(const int* __restrict__ srcs, const int* __restrict__ dsts,
                            const int* __restrict__ rowstart, int* __restrict__ cursor,
                            int* __restrict__ csr, int E_, int Etot_) {
    int i = blockIdx.x * blockDim.x + threadIdx.x;
    if (i >= Etot_) return;
    int s, d;
    if (i < E_) { s = srcs[i]; d = dsts[i]; } else { s = i - E_; d = s; }
    int pos = rowstart[d] + atomicAdd(&cursor[d], 1);
    csr[pos] = s;
}

__global__ void goff_kernel(const int* __restrict__ batch, int* __restrict__ goff, int nN, int nG) {
    int g = blockIdx.x * blockDim.x + threadIdx.x;
    if (g > nG) return;
    if (g == nG) { goff[g] = nN; return; }
    int lo = 0, hi = nN;
    while (lo < hi) { int mid = (lo + hi) >> 1; if (batch[mid] < g) lo = mid + 1; else hi = mid; }
    goff[g] = lo;
}

// ---------------- GEMM: xl = h@Wl, xr = h@Wr (K=64 fixed) ----------------
// D = output dim (64 or 128). 256 threads, TPN=D/16 threads/node, 16 outputs/thread.

template <int D>
__global__ void gemm2_kernel(const float* __restrict__ x, const float* __restrict__ Wl,
                             const float* __restrict__ Wr, float* __restrict__ xl,
                             float* __restrict__ xr, int nN) {
    constexpr int TPN = D / 16;
    constexpr int NPB = 256 / TPN;
    __shared__ float w_s[64 * D];
    __shared__ float x_s[NPB][65];
    int tid = threadIdx.x;
    int node0 = blockIdx.x * NPB;
    for (int i = tid; i < NPB * 64; i += 256) {
        int r = i >> 6, c = i & 63;
        int n = node0 + r;
        x_s[r][c] = (n < nN) ? x[(size_t)n * 64 + c] : 0.f;
    }
    int local = tid / TPN, j0 = (tid % TPN) * 16;
    int n = node0 + local;
    float acc[16];

    // phase L
    for (int i = tid; i < 64 * D; i += 256) w_s[i] = Wl[i];
    __syncthreads();
#pragma unroll
    for (int j = 0; j < 16; ++j) acc[j] = 0.f;
    for (int k = 0; k < 64; ++k) {
        float xv = x_s[local][k];
        const float* wrow = &w_s[k * D + j0];
#pragma unroll
        for (int j = 0; j < 16; ++j) acc[j] = fmaf(xv, wrow[j], acc[j]);
    }
    if (n < nN) {
#pragma unroll
        for (int j = 0; j < 16; ++j) xl[(size_t)n * D + j0 + j] = acc[j];
    }
    __syncthreads();

    // phase R
    for (int i = tid; i < 64 * D; i += 256) w_s[i] = Wr[i];
    __syncthreads();
#pragma unroll
    for (int j = 0; j < 16; ++j) acc[j] = 0.f;
    for (int k = 0; k < 64; ++k) {
        float xv = x_s[local][k];
        const float* wrow = &w_s[k * D + j0];
#pragma unroll
        for (int j = 0; j < 16; ++j) acc[j] = fmaf(xv, wrow[j], acc[j]);
    }
    if (n < nN) {
#pragma unroll
        for (int j = 0; j < 16; ++j) xr[(size_t)n * D + j0 + j] = acc[j];
    }
}

// ---------------- Aggregate (layers 1-2): D=64, H=4, C=16, concat ----------------
// One wave per node, lane = channel. Online softmax per head (16-lane groups).

__global__ void agg64_kernel(const float* __restrict__ xl, const float* __restrict__ xr,
                             const int* __restrict__ rowstart, const int* __restrict__ csr,
                             const float* __restrict__ att, const float* __restrict__ bias,
                             float* __restrict__ out, int nN) {
    int wid = (blockIdx.x * blockDim.x + threadIdx.x) >> 6;
    int lane = threadIdx.x & 63;
    if (wid >= nN) return;
    float attv = att[lane];
    float xrv = xr[(size_t)wid * 64 + lane];
    int rs = rowstart[wid], re = rowstart[wid + 1];
    float mx = -1e30f, den = 0.f, acc = 0.f;
    int src = csr[rs];
    float xlv = xl[(size_t)src * 64 + lane];
    for (int i = rs; i < re; ++i) {
        float cur = xlv;
        if (i + 1 < re) {
            int ns = csr[i + 1];
            xlv = xl[(size_t)ns * 64 + lane];
        }
        float s = cur + xrv;
        float m = s > 0.f ? s : LEAKY * s;
        float p = m * attv;
        p += __shfl_xor(p, 1);
        p += __shfl_xor(p, 2);
        p += __shfl_xor(p, 4);
        p += __shfl_xor(p, 8);
        float nm = fmaxf(mx, p);
        float sc = __expf(mx - nm);
        float w = __expf(p - nm);
        den = den * sc + w;
        acc = acc * sc + w * cur;
        mx = nm;
    }
    out[(size_t)wid * 64 + lane] = acc / den + bias[lane];
}

// ---------------- Aggregate (layer 3): D=128, H=4, C=32, head-mean ----------------

__global__ void agg128_mean_kernel(const float* __restrict__ xl, const float* __restrict__ xr,
                                   const int* __restrict__ rowstart, const int* __restrict__ csr,
                                   const float* __restrict__ att, const float* __restrict__ bias,
                                   float* __restrict__ out, int nN) {
    int wid = (blockIdx.x * blockDim.x + threadIdx.x) >> 6;
    int lane = threadIdx.x & 63;
    if (wid >= nN) return;
    float attA = att[lane], attB = att[lane + 64];
    float xrA = xr[(size_t)wid * 128 + lane];
    float xrB = xr[(size_t)wid * 128 + 64 + lane];
    int rs = rowstart[wid], re = rowstart[wid + 1];
    float mxA = -1e30f, denA = 0.f, accA = 0.f;
    float mxB = -1e30f, denB = 0.f, accB = 0.f;
    int src = csr[rs];
    float xlA = xl[(size_t)src * 128 + lane];
    float xlB = xl[(size_t)src * 128 + 64 + lane];
    for (int i = rs; i < re; ++i) {
        float curA = xlA, curB = xlB;
        if (i + 1 < re) {
            int ns = csr[i + 1];
            xlA = xl[(size_t)ns * 128 + lane];
            xlB = xl[(size_t)ns * 128 + 64 + lane];
        }
        float sA = curA + xrA, sB = curB + xrB;
        float mA = sA > 0.f ? sA : LEAKY * sA;
        float mB = sB > 0.f ? sB : LEAKY * sB;
        float pA = mA * attA, pB = mB * attB;
        pA += __shfl_xor(pA, 1);  pB += __shfl_xor(pB, 1);
        pA += __shfl_xor(pA, 2);  pB += __shfl_xor(pB, 2);
        pA += __shfl_xor(pA, 4);  pB += __shfl_xor(pB, 4);
        pA += __shfl_xor(pA, 8);  pB += __shfl_xor(pB, 8);
        pA += __shfl_xor(pA, 16); pB += __shfl_xor(pB, 16);
        float nmA = fmaxf(mxA, pA);
        float scA = __expf(mxA - nmA);
        float wA = __expf(pA - nmA);
        denA = denA * scA + wA;
        accA = accA * scA + wA * curA;
        mxA = nmA;
        float nmB = fmaxf(mxB, pB);
        float scB = __expf(mxB - nmB);
        float wB = __expf(pB - nmB);
        denB = denB * scB + wB;
        accB = accB * scB + wB * curB;
        mxB = nmB;
    }
    float t = accA / denA + accB / denB;
    t += __shfl_xor(t, 32);
    if (lane < 32) out[(size_t)wid * 32 + lane] = t * 0.25f + bias[lane];
}

// ---------------- GraphNorm + ReLU (layers 1-2, D=64) ----------------

__global__ void gnorm_relu_kernel(const float* __restrict__ in, const int* __restrict__ goff,
                                  const float* __restrict__ w, const float* __restrict__ b,
                                  const float* __restrict__ a, float* __restrict__ out) {
    int g = blockIdx.x;
    int start = goff[g], end = goff[g + 1];
    int tid = threadIdx.x;
    int c = tid & 63, sub = tid >> 6;
    float s1 = 0.f, s2 = 0.f;
    for (int n = start + sub; n < end; n += 4) {
        float v = in[(size_t)n * 64 + c];
        s1 += v; s2 += v * v;
    }
    __shared__ float l1[4][64], l2[4][64];
    __shared__ float sc_s[64], sh_s[64];
    l1[sub][c] = s1; l2[sub][c] = s2;
    __syncthreads();
    if (tid < 64) {
        float S1 = l1[0][c] + l1[1][c] + l1[2][c] + l1[3][c];
        float S2 = l2[0][c] + l2[1][c] + l2[2][c] + l2[3][c];
        int cn = end - start;
        float cnt = (float)(cn > 1 ? cn : 1);
        float mu = S1 / cnt;
        float am = a[c] * mu;
        float var = S2 / cnt - 2.f * am * mu + am * am;
        float inv = rsqrtf(var + EPS_GN);
        float sc = w[c] * inv;
        sc_s[c] = sc;
        sh_s[c] = b[c] - sc * am;
    }
    __syncthreads();
    float sc = sc_s[c], sh = sh_s[c];
    for (int n = start + sub; n < end; n += 4) {
        float v = in[(size_t)n * 64 + c];
        out[(size_t)n * 64 + c] = fmaxf(fmaf(sc, v, sh), 0.f);
    }
}

// ---------------- GraphNorm + ReLU + mean-pool + linear (layer 3, D=32) ----------------

__global__ void gnorm3_pool_lin_kernel(const float* __restrict__ in, const int* __restrict__ goff,
                                       const float* __restrict__ w, const float* __restrict__ b,
                                       const float* __restrict__ a, const float* __restrict__ Wlin,
                                       const float* __restrict__ blin, float* __restrict__ out) {
    int g = blockIdx.x;
    int start = goff[g], end = goff[g + 1];
    int tid = threadIdx.x;
    int c = tid & 31, sub = tid >> 5;
    float s1 = 0.f, s2 = 0.f;
    for (int n = start + sub; n < end; n += 8) {
        float v = in[(size_t)n * 32 + c];
        s1 += v; s2 += v * v;
    }
    __shared__ float l1[8][32], l2[8][32];
    __shared__ float sc_s[32], sh_s[32];
    l1[sub][c] = s1; l2[sub][c] = s2;
    __syncthreads();
    int cn = end - start;
    float cnt = (float)(cn > 1 ? cn : 1);
    if (tid < 32) {
        float S1 = 0.f, S2 = 0.f;
#pragma unroll
        for (int s = 0; s < 8; ++s) { S1 += l1[s][c]; S2 += l2[s][c]; }
        float mu = S1 / cnt;
        float am = a[c] * mu;
        float var = S2 / cnt - 2.f * am * mu + am * am;
        float inv = rsqrtf(var + EPS_GN);
        float sc = w[c] * inv;
        sc_s[c] = sc;
        sh_s[c] = b[c] - sc * am;
    }
    __syncthreads();
    float sc = sc_s[c], sh = sh_s[c];
    float ps = 0.f;
    for (int n = start + sub; n < end; n += 8) {
        float v = in[(size_t)n * 32 + c];
        ps += fmaxf(fmaf(sc, v, sh), 0.f);
    }
    __syncthreads();
    l1[sub][c] = ps;
    __syncthreads();
    if (tid < 32) {
        float S = 0.f;
#pragma unroll
        for (int s = 0; s < 8; ++s) S += l1[s][c];
        sc_s[c] = S / cnt;  // pooled mean
    }
    __syncthreads();
    if (tid < 2) {
        float accv = blin[tid];
        for (int cc = 0; cc < 32; ++cc) accv = fmaf(sc_s[cc], Wlin[cc * 2 + tid], accv);
        out[g * 2 + tid] = accv;
    }
}

// ---------------- launch ----------------

extern "C" void kernel_launch(void* const* d_in, const int* in_sizes, int n_in,
                              void* d_out, int out_size, void* d_ws, size_t ws_size,
                              hipStream_t stream) {
    const float* x    = (const float*)d_in[0];
    const int*  eidx  = (const int*)d_in[1];
    const int*  batch = (const int*)d_in[2];
    const float* Wl1 = (const float*)d_in[3];
    const float* Wr1 = (const float*)d_in[4];
    const float* att1 = (const float*)d_in[5];
    const float* b1 = (const float*)d_in[6];
    const float* g1w = (const float*)d_in[7];
    const float* g1b = (const float*)d_in[8];
    const float* g1a = (const float*)d_in[9];
    const float* Wl2 = (const float*)d_in[10];
    const float* Wr2 = (const float*)d_in[11];
    const float* att2 = (const float*)d_in[12];
    const float* b2 = (const float*)d_in[13];
    const float* g2w = (const float*)d_in[14];
    const float* g2b = (const float*)d_in[15];
    const float* g2a = (const float*)d_in[16];
    const float* Wl3 = (const float*)d_in[17];
    const float* Wr3 = (const float*)d_in[18];
    const float* att3 = (const float*)d_in[19];
    const float* b3 = (const float*)d_in[20];
    const float* g3w = (const float*)d_in[21];
    const float* g3b = (const float*)d_in[22];
    const float* g3a = (const float*)d_in[23];
    const float* Wlin = (const float*)d_in[24];
    const float* blin = (const float*)d_in[25];
    float* outp = (float*)d_out;

    const int N = in_sizes[0] / 64;
    const int E = in_sizes[1] / 2;
    const int Etot = N + E;
    const int G = out_size / 2;
    const int NB = (N + 255) / 256;

    float* ws = (float*)d_ws;
    float* xl   = ws;
    float* xr   = xl + (size_t)N * 128;
    float* agg  = xr + (size_t)N * 128;
    float* hbuf = agg + (size_t)N * 64;
    int* deg      = (int*)(hbuf + (size_t)N * 64);
    int* cursor   = deg + N;
    int* rowstart = cursor + N;
    int* csr      = rowstart + (N + 1);
    int* bsum     = csr + Etot;
    int* bofs     = bsum + NB;
    int* goff     = bofs + NB;

    const int* src_idx = eidx;
    const int* dst_idx = eidx + E;

    // CSR build
    zero_int_kernel<<<(2 * N + 255) / 256, 256, 0, stream>>>(deg, 2 * N);
    hist_kernel<<<(Etot + 255) / 256, 256, 0, stream>>>(dst_idx, deg, E, Etot);
    scan1_kernel<<<NB, 256, 0, stream>>>(deg, bsum, N);
    scan2_kernel<<<1, 64, 0, stream>>>(bsum, bofs, NB, rowstart, N);
    scan3_kernel<<<NB, 256, 0, stream>>>(deg, bofs, rowstart, N);
    fill_kernel<<<(Etot + 255) / 256, 256, 0, stream>>>(src_idx, dst_idx, rowstart, cursor, csr, E, Etot);
    goff_kernel<<<1, 128, 0, stream>>>(batch, goff, N, G);

    dim3 blk(256);
    int aggGrid = (N + 3) / 4;

    // Layer 1
    gemm2_kernel<64><<<(N + 63) / 64, blk, 0, stream>>>(x, Wl1, Wr1, xl, xr, N);
    agg64_kernel<<<aggGrid, blk, 0, stream>>>(xl, xr, rowstart, csr, att1, b1, agg, N);
    gnorm_relu_kernel<<<G, blk, 0, stream>>>(agg, goff, g1w, g1b, g1a, hbuf);

    // Layer 2
    gemm2_kernel<64><<<(N + 63) / 64, blk, 0, stream>>>(hbuf, Wl2, Wr2, xl, xr, N);
    agg64_kernel<<<aggGrid, blk, 0, stream>>>(xl, xr, rowstart, csr, att2, b2, agg, N);
    gnorm_relu_kernel<<<G, blk, 0, stream>>>(agg, goff, g2w, g2b, g2a, hbuf);

    // Layer 3
    gemm2_kernel<128><<<(N + 31) / 32, blk, 0, stream>>>(hbuf, Wl3, Wr3, xl, xr, N);
    agg128_mean_kernel<<<aggGrid, blk, 0, stream>>>(xl, xr, rowstart, csr, att3, b3, agg, N);
    gnorm3_pool_lin_kernel<<<G, blk, 0, stream>>>(agg, goff, g3w, g3b, g3a, Wlin, blin, outp);
}

// Round 2
// 781.711 us; speedup vs baseline: 1.6792x; 1.6792x over previous
//
#include <hip/hip_runtime.h>
#include <hip/hip_bf16.h>

#define LEAKY 0.2f
#define EPS_GN 1e-5f
#define NEG_BIG -3.0e38f

// ---------------- CSR build ----------------

__global__ void zero_int_kernel(int* __restrict__ p, int n) {
    int i = blockIdx.x * blockDim.x + threadIdx.x;
    if (i < n) p[i] = 0;
}

__global__ void hist_kernel(const int* __restrict__ dst, int* __restrict__ deg, int E_, int Etot_) {
    int i = blockIdx.x * blockDim.x + threadIdx.x;
    if (i >= Etot_) return;
    int d = (i < E_) ? dst[i] : (i - E_);
    atomicAdd(&deg[d], 1);
}

__global__ void scan1_kernel(const int* __restrict__ deg, int* __restrict__ bsum, int nN) {
    __shared__ int sd[256];
    int i = blockIdx.x * 256 + threadIdx.x;
    sd[threadIdx.x] = (i < nN) ? deg[i] : 0;
    __syncthreads();
    for (int off = 128; off > 0; off >>= 1) {
        if (threadIdx.x < off) sd[threadIdx.x] += sd[threadIdx.x + off];
        __syncthreads();
    }
    if (threadIdx.x == 0) bsum[blockIdx.x] = sd[0];
}

__global__ void scan2_kernel(const int* __restrict__ bsum, int* __restrict__ bofs, int nb,
                             int* __restrict__ rowstart, int nN) {
    if (threadIdx.x == 0 && blockIdx.x == 0) {
        int run = 0;
        for (int i = 0; i < nb; ++i) { bofs[i] = run; run += bsum[i]; }
        rowstart[nN] = run;
    }
}

__global__ void scan3_kernel(const int* __restrict__ deg, const int* __restrict__ bofs,
                             int* __restrict__ rowstart, int nN) {
    __shared__ int sd[256];
    int i = blockIdx.x * 256 + threadIdx.x;
    int v = (i < nN) ? deg[i] : 0;
    sd[threadIdx.x] = v;
    __syncthreads();
    for (int off = 1; off < 256; off <<= 1) {
        int t = (threadIdx.x >= off) ? sd[threadIdx.x - off] : 0;
        __syncthreads();
        sd[threadIdx.x] += t;
        __syncthreads();
    }
    if (i < nN) rowstart[i] = bofs[blockIdx.x] + sd[threadIdx.x] - v;
}

__global__ void fill_kernel(const int* __restrict__ srcs, const int* __restrict__ dsts,
                            const int* __restrict__ rowstart, int* __restrict__ cursor,
                            int* __restrict__ csr, int E_, int Etot_) {
    int i = blockIdx.x * blockDim.x + threadIdx.x;
    if (i >= Etot_) return;
    int s, d;
    if (i < E_) { s = srcs[i]; d = dsts[i]; } else { s = i - E_; d = s; }
    int pos = rowstart[d] + atomicAdd(&cursor[d], 1);
    csr[pos] = s;
}

__global__ void goff_kernel(const int* __restrict__ batch, int* __restrict__ goff, int nN, int nG) {
    int g = blockIdx.x * blockDim.x + threadIdx.x;
    if (g > nG) return;
    if (g == nG) { goff[g] = nN; return; }
    int lo = 0, hi = nN;
    while (lo < hi) { int mid = (lo + hi) >> 1; if (batch[mid] < g) lo = mid + 1; else hi = mid; }
    goff[g] = lo;
}

// ---------------- GEMM: xl = h@Wl, xr = h@Wr (K=64 fixed) ----------------

template <int D>
__global__ void gemm2_kernel(const float* __restrict__ x, const float* __restrict__ Wl,
                             const float* __restrict__ Wr, float* __restrict__ xl,
                             float* __restrict__ xr, int nN) {
    constexpr int TPN = D / 16;
    constexpr int NPB = 256 / TPN;
    __shared__ float w_s[64 * D];
    __shared__ float x_s[NPB][65];
    int tid = threadIdx.x;
    int node0 = blockIdx.x * NPB;
    for (int i = tid; i < NPB * 64; i += 256) {
        int r = i >> 6, c = i & 63;
        int n = node0 + r;
        x_s[r][c] = (n < nN) ? x[(size_t)n * 64 + c] : 0.f;
    }
    int local = tid / TPN, j0 = (tid % TPN) * 16;
    int n = node0 + local;
    float acc[16];

    for (int i = tid; i < 64 * D; i += 256) w_s[i] = Wl[i];
    __syncthreads();
#pragma unroll
    for (int j = 0; j < 16; ++j) acc[j] = 0.f;
    for (int k = 0; k < 64; ++k) {
        float xv = x_s[local][k];
        const float* wrow = &w_s[k * D + j0];
#pragma unroll
        for (int j = 0; j < 16; ++j) acc[j] = fmaf(xv, wrow[j], acc[j]);
    }
    if (n < nN) {
#pragma unroll
        for (int j = 0; j < 16; ++j) xl[(size_t)n * D + j0 + j] = acc[j];
    }
    __syncthreads();

    for (int i = tid; i < 64 * D; i += 256) w_s[i] = Wr[i];
    __syncthreads();
#pragma unroll
    for (int j = 0; j < 16; ++j) acc[j] = 0.f;
    for (int k = 0; k < 64; ++k) {
        float xv = x_s[local][k];
        const float* wrow = &w_s[k * D + j0];
#pragma unroll
        for (int j = 0; j < 16; ++j) acc[j] = fmaf(xv, wrow[j], acc[j]);
    }
    if (n < nN) {
#pragma unroll
        for (int j = 0; j < 16; ++j) xr[(size_t)n * D + j0 + j] = acc[j];
    }
}

// ---------------- Aggregate layer 1-2: D=64, H=4, C=16, concat ----------------
// float4/lane, 16 lanes/edge, 4 edge substreams/wave, online softmax, merge at end.

__global__ void agg64_kernel(const float* __restrict__ xl, const float* __restrict__ xr,
                             const int* __restrict__ rowstart, const int* __restrict__ csr,
                             const float* __restrict__ att, const float* __restrict__ bias,
                             float* __restrict__ out, int nN) {
    int wid = (blockIdx.x * blockDim.x + threadIdx.x) >> 6;
    int lane = threadIdx.x & 63;
    if (wid >= nN) return;
    int c4 = lane & 15;          // channels c4*4 .. c4*4+3; head = c4>>2
    int sg = lane >> 4;          // 4 edge substreams
    const float4* xl4 = (const float4*)xl;
    float4 attv = ((const float4*)att)[c4];
    float4 xrv  = ((const float4*)xr)[(size_t)wid * 16 + c4];
    int rs = rowstart[wid], re = rowstart[wid + 1];
    int nIt = (re - rs + 3) >> 2;
    float mx = -1e30f, den = 0.f;
    float4 acc = make_float4(0.f, 0.f, 0.f, 0.f);
    int i = rs + sg;
    bool v = i < re;
    int ic = v ? i : re - 1;
    int s = csr[ic];
    float4 xv = xl4[(size_t)s * 16 + c4];
    for (int it = 0; it < nIt; ++it) {
        float4 cur = xv;
        bool vv = v;
        i += 4;
        v = i < re;
        ic = v ? i : re - 1;
        s = csr[ic];
        float4 mm;
        mm.x = cur.x + xrv.x; mm.y = cur.y + xrv.y;
        mm.z = cur.z + xrv.z; mm.w = cur.w + xrv.w;
        mm.x = fmaxf(mm.x, LEAKY * mm.x);
        mm.y = fmaxf(mm.y, LEAKY * mm.y);
        mm.z = fmaxf(mm.z, LEAKY * mm.z);
        mm.w = fmaxf(mm.w, LEAKY * mm.w);
        float p = mm.x * attv.x;
        p = fmaf(mm.y, attv.y, p);
        p = fmaf(mm.z, attv.z, p);
        p = fmaf(mm.w, attv.w, p);
        p += __shfl_xor(p, 1);
        p += __shfl_xor(p, 2);
        xv = xl4[(size_t)s * 16 + c4];   // prefetch next edge
        if (!vv) p = NEG_BIG;
        float nm = fmaxf(mx, p);
        float sc = __expf(mx - nm);
        float w  = __expf(p - nm);
        den = den * sc + w;
        acc.x = fmaf(acc.x, sc, w * cur.x);
        acc.y = fmaf(acc.y, sc, w * cur.y);
        acc.z = fmaf(acc.z, sc, w * cur.z);
        acc.w = fmaf(acc.w, sc, w * cur.w);
        mx = nm;
    }
#pragma unroll
    for (int off = 16; off <= 32; off <<= 1) {
        float om = __shfl_xor(mx, off);
        float od = __shfl_xor(den, off);
        float ox = __shfl_xor(acc.x, off);
        float oy = __shfl_xor(acc.y, off);
        float oz = __shfl_xor(acc.z, off);
        float ow = __shfl_xor(acc.w, off);
        float nm = fmaxf(mx, om);
        float s1 = __expf(mx - nm), s2 = __expf(om - nm);
        den = den * s1 + od * s2;
        acc.x = acc.x * s1 + ox * s2;
        acc.y = acc.y * s1 + oy * s2;
        acc.z = acc.z * s1 + oz * s2;
        acc.w = acc.w * s1 + ow * s2;
        mx = nm;
    }
    if (lane < 16) {
        float4 bv = ((const float4*)bias)[c4];
        float inv = 1.f / den;
        float4 r;
        r.x = acc.x * inv + bv.x;
        r.y = acc.y * inv + bv.y;
        r.z = acc.z * inv + bv.z;
        r.w = acc.w * inv + bv.w;
        ((float4*)out)[(size_t)wid * 16 + c4] = r;
    }
}

// ---------------- Aggregate layer 3: D=128, H=4, C=32, head-mean ----------------
// float4/lane, 32 lanes/edge, 2 edge substreams/wave.

__global__ void agg128_mean_kernel(const float* __restrict__ xl, const float* __restrict__ xr,
                                   const int* __restrict__ rowstart, const int* __restrict__ csr,
                                   const float* __restrict__ att, const float* __restrict__ bias,
                                   float* __restrict__ out, int nN) {
    int wid = (blockIdx.x * blockDim.x + threadIdx.x) >> 6;
    int lane = threadIdx.x & 63;
    if (wid >= nN) return;
    int c4 = lane & 31;          // channels c4*4 .. c4*4+3; head = c4>>3
    int sg = lane >> 5;          // 2 edge substreams
    const float4* xl4 = (const float4*)xl;
    float4 attv = ((const float4*)att)[c4];
    float4 xrv  = ((const float4*)xr)[(size_t)wid * 32 + c4];
    int rs = rowstart[wid], re = rowstart[wid + 1];
    int nIt = (re - rs + 1) >> 1;
    float mx = -1e30f, den = 0.f;
    float4 acc = make_float4(0.f, 0.f, 0.f, 0.f);
    int i = rs + sg;
    bool v = i < re;
    int ic = v ? i : re - 1;
    int s = csr[ic];
    float4 xv = xl4[(size_t)s * 32 + c4];
    for (int it = 0; it < nIt; ++it) {
        float4 cur = xv;
        bool vv = v;
        i += 2;
        v = i < re;
        ic = v ? i : re - 1;
        s = csr[ic];
        float4 mm;
        mm.x = cur.x + xrv.x; mm.y = cur.y + xrv.y;
        mm.z = cur.z + xrv.z; mm.w = cur.w + xrv.w;
        mm.x = fmaxf(mm.x, LEAKY * mm.x);
        mm.y = fmaxf(mm.y, LEAKY * mm.y);
        mm.z = fmaxf(mm.z, LEAKY * mm.z);
        mm.w = fmaxf(mm.w, LEAKY * mm.w);
        float p = mm.x * attv.x;
        p = fmaf(mm.y, attv.y, p);
        p = fmaf(mm.z, attv.z, p);
        p = fmaf(mm.w, attv.w, p);
        p += __shfl_xor(p, 1);
        p += __shfl_xor(p, 2);
        p += __shfl_xor(p, 4);
        xv = xl4[(size_t)s * 32 + c4];   // prefetch next edge
        if (!vv) p = NEG_BIG;
        float nm = fmaxf(mx, p);
        float sc = __expf(mx - nm);
        float w  = __expf(p - nm);
        den = den * sc + w;
        acc.x = fmaf(acc.x, sc, w * cur.x);
        acc.y = fmaf(acc.y, sc, w * cur.y);
        acc.z = fmaf(acc.z, sc, w * cur.z);
        acc.w = fmaf(acc.w, sc, w * cur.w);
        mx = nm;
    }
    {
        int off = 32;
        float om = __shfl_xor(mx, off);
        float od = __shfl_xor(den, off);
        float ox = __shfl_xor(acc.x, off);
        float oy = __shfl_xor(acc.y, off);
        float oz = __shfl_xor(acc.z, off);
        float ow = __shfl_xor(acc.w, off);
        float nm = fmaxf(mx, om);
        float s1 = __expf(mx - nm), s2 = __expf(om - nm);
        den = den * s1 + od * s2;
        acc.x = acc.x * s1 + ox * s2;
        acc.y = acc.y * s1 + oy * s2;
        acc.z = acc.z * s1 + oz * s2;
        acc.w = acc.w * s1 + ow * s2;
        mx = nm;
    }
    float inv = 1.f / den;
    float4 r;
    r.x = acc.x * inv; r.y = acc.y * inv; r.z = acc.z * inv; r.w = acc.w * inv;
    // head mean: sum lanes differing in c4 bits 3,4 (heads), then /4
    r.x += __shfl_xor(r.x, 8);  r.y += __shfl_xor(r.y, 8);
    r.z += __shfl_xor(r.z, 8);  r.w += __shfl_xor(r.w, 8);
    r.x += __shfl_xor(r.x, 16); r.y += __shfl_xor(r.y, 16);
    r.z += __shfl_xor(r.z, 16); r.w += __shfl_xor(r.w, 16);
    if (lane < 8) {
        float4 bv = ((const float4*)bias)[lane];
        float4 o;
        o.x = r.x * 0.25f + bv.x;
        o.y = r.y * 0.25f + bv.y;
        o.z = r.z * 0.25f + bv.z;
        o.w = r.w * 0.25f + bv.w;
        ((float4*)out)[(size_t)wid * 8 + lane] = o;
    }
}

// ---------------- GraphNorm: stats -> finalize -> apply ----------------

template <int D>
__global__ void gnorm_stats_kernel(const float* __restrict__ in, const int* __restrict__ goff,
                                   float* __restrict__ stats, int SPLIT) {
    int g = blockIdx.x / SPLIT, part = blockIdx.x % SPLIT;
    int start = goff[g], end = goff[g + 1];
    constexpr int RPB = 256 / D;
    int tid = threadIdx.x;
    int c = tid % D, sub = tid / D;
    float s1 = 0.f, s2 = 0.f;
    for (int n = start + part * RPB + sub; n < end; n += SPLIT * RPB) {
        float v = in[(size_t)n * D + c];
        s1 += v; s2 += v * v;
    }
    __shared__ float l1[256], l2[256];
    l1[tid] = s1; l2[tid] = s2;
    __syncthreads();
    if (tid < D) {
        for (int s = 1; s < RPB; ++s) { s1 += l1[s * D + tid]; s2 += l2[s * D + tid]; }
        atomicAdd(&stats[(size_t)g * 2 * D + tid], s1);
        atomicAdd(&stats[(size_t)g * 2 * D + D + tid], s2);
    }
}

template <int D>
__global__ void gnorm_finalize_kernel(const float* __restrict__ stats, const int* __restrict__ goff,
                                      const float* __restrict__ w, const float* __restrict__ b,
                                      const float* __restrict__ a, float* __restrict__ param) {
    int g = blockIdx.x, c = threadIdx.x;
    if (c >= D) return;
    int cn = goff[g + 1] - goff[g];
    float cnt = (float)(cn > 1 ? cn : 1);
    float S1 = stats[(size_t)g * 2 * D + c], S2 = stats[(size_t)g * 2 * D + D + c];
    float mu = S1 / cnt;
    float am = a[c] * mu;
    float var = S2 / cnt - 2.f * am * mu + am * am;
    float sc = w[c] * rsqrtf(var + EPS_GN);
    param[(size_t)g * 2 * D + c] = sc;
    param[(size_t)g * 2 * D + D + c] = b[c] - sc * am;
}

// apply for D=64 (layers 1,2): norm + relu, fully parallel, float4
__global__ void gnorm_apply_kernel(const float* __restrict__ in, const int* __restrict__ batch,
                                   const float* __restrict__ param, float* __restrict__ out, int nN) {
    int idx = blockIdx.x * blockDim.x + threadIdx.x;
    if (idx >= nN * 16) return;
    int n = idx >> 4, c4 = idx & 15;
    int g = batch[n];
    float4 v  = ((const float4*)in)[idx];
    float4 sc = ((const float4*)(param + (size_t)g * 128))[c4];
    float4 sh = ((const float4*)(param + (size_t)g * 128 + 64))[c4];
    float4 r;
    r.x = fmaxf(fmaf(sc.x, v.x, sh.x), 0.f);
    r.y = fmaxf(fmaf(sc.y, v.y, sh.y), 0.f);
    r.z = fmaxf(fmaf(sc.z, v.z, sh.z), 0.f);
    r.w = fmaxf(fmaf(sc.w, v.w, sh.w), 0.f);
    ((float4*)out)[idx] = r;
}

// layer-3 tail: norm+relu+partial pooled sums (D=32)
__global__ void pool3_kernel(const float* __restrict__ in, const int* __restrict__ goff,
                             const float* __restrict__ param, float* __restrict__ pooled, int SPLIT) {
    int g = blockIdx.x / SPLIT, part = blockIdx.x % SPLIT;
    int start = goff[g], end = goff[g + 1];
    int tid = threadIdx.x;
    int c = tid & 31, sub = tid >> 5;  // 8 rows in flight
    float sc = param[(size_t)g * 64 + c], sh = param[(size_t)g * 64 + 32 + c];
    float s = 0.f;
    for (int n = start + part * 8 + sub; n < end; n += SPLIT * 8)
        s += fmaxf(fmaf(sc, in[(size_t)n * 32 + c], sh), 0.f);
    __shared__ float l[256];
    l[tid] = s;
    __syncthreads();
    if (tid < 32) {
        for (int q = 1; q < 8; ++q) s += l[q * 32 + tid];
        atomicAdd(&pooled[(size_t)g * 32 + tid], s);
    }
}

__global__ void lin_kernel(const float* __restrict__ pooled, const int* __restrict__ goff,
                           const float* __restrict__ Wlin, const float* __restrict__ blin,
                           float* __restrict__ out, int nG) {
    int idx = blockIdx.x * blockDim.x + threadIdx.x;
    if (idx >= nG * 2) return;
    int g = idx >> 1, o = idx & 1;
    int cn = goff[g + 1] - goff[g];
    float inv = 1.f / (float)(cn > 1 ? cn : 1);
    float acc = blin[o];
    for (int c = 0; c < 32; ++c) acc = fmaf(pooled[(size_t)g * 32 + c] * inv, Wlin[c * 2 + o], acc);
    out[idx] = acc;
}

// ---------------- launch ----------------

extern "C" void kernel_launch(void* const* d_in, const int* in_sizes, int n_in,
                              void* d_out, int out_size, void* d_ws, size_t ws_size,
                              hipStream_t stream) {
    const float* x    = (const float*)d_in[0];
    const int*  eidx  = (const int*)d_in[1];
    const int*  batch = (const int*)d_in[2];
    const float* Wl1 = (const float*)d_in[3];
    const float* Wr1 = (const float*)d_in[4];
    const float* att1 = (const float*)d_in[5];
    const float* b1 = (const float*)d_in[6];
    const float* g1w = (const float*)d_in[7];
    const float* g1b = (const float*)d_in[8];
    const float* g1a = (const float*)d_in[9];
    const float* Wl2 = (const float*)d_in[10];
    const float* Wr2 = (const float*)d_in[11];
    const float* att2 = (const float*)d_in[12];
    const float* b2 = (const float*)d_in[13];
    const float* g2w = (const float*)d_in[14];
    const float* g2b = (const float*)d_in[15];
    const float* g2a = (const float*)d_in[16];
    const float* Wl3 = (const float*)d_in[17];
    const float* Wr3 = (const float*)d_in[18];
    const float* att3 = (const float*)d_in[19];
    const float* b3 = (const float*)d_in[20];
    const float* g3w = (const float*)d_in[21];
    const float* g3b = (const float*)d_in[22];
    const float* g3a = (const float*)d_in[23];
    const float* Wlin = (const float*)d_in[24];
    const float* blin = (const float*)d_in[25];
    float* outp = (float*)d_out;

    const int N = in_sizes[0] / 64;
    const int E = in_sizes[1] / 2;
    const int Etot = N + E;
    const int G = out_size / 2;
    const int NB = (N + 255) / 256;
    const int SPLIT = 16;

    float* ws = (float*)d_ws;
    float* xl    = ws;
    float* xr    = xl + (size_t)N * 128;
    float* agg   = xr + (size_t)N * 128;
    float* hbuf  = agg + (size_t)N * 64;
    float* stats = hbuf + (size_t)N * 64;        // stats1(128G) stats2(128G) stats3(64G) pooled(32G)
    float* stats1 = stats;
    float* stats2 = stats1 + (size_t)G * 128;
    float* stats3 = stats2 + (size_t)G * 128;
    float* pooled = stats3 + (size_t)G * 64;
    float* param  = pooled + (size_t)G * 32;     // G*128, reused per layer
    int* deg      = (int*)(param + (size_t)G * 128);
    int* cursor   = deg + N;
    int* rowstart = cursor + N;
    int* csr      = rowstart + (N + 1);
    int* bsum     = csr + Etot;
    int* bofs     = bsum + NB;
    int* goff     = bofs + NB;

    const int* src_idx = eidx;
    const int* dst_idx = eidx + E;

    // zero deg/cursor + float stats (bit-zero == 0.0f)
    zero_int_kernel<<<(2 * N + 255) / 256, 256, 0, stream>>>(deg, 2 * N);
    zero_int_kernel<<<(G * 352 + 255) / 256, 256, 0, stream>>>((int*)stats, G * 352);

    hist_kernel<<<(Etot + 255) / 256, 256, 0, stream>>>(dst_idx, deg, E, Etot);
    scan1_kernel<<<NB, 256, 0, stream>>>(deg, bsum, N);
    scan2_kernel<<<1, 64, 0, stream>>>(bsum, bofs, NB, rowstart, N);
    scan3_kernel<<<NB, 256, 0, stream>>>(deg, bofs, rowstart, N);
    fill_kernel<<<(Etot + 255) / 256, 256, 0, stream>>>(src_idx, dst_idx, rowstart, cursor, csr, E, Etot);
    goff_kernel<<<1, 128, 0, stream>>>(batch, goff, N, G);

    dim3 blk(256);
    int aggGrid = (N + 3) / 4;
    int applyGrid = (N * 16 + 255) / 256;

    // Layer 1
    gemm2_kernel<64><<<(N + 63) / 64, blk, 0, stream>>>(x, Wl1, Wr1, xl, xr, N);
    agg64_kernel<<<aggGrid, blk, 0, stream>>>(xl, xr, rowstart, csr, att1, b1, agg, N);
    gnorm_stats_kernel<64><<<G * SPLIT, blk, 0, stream>>>(agg, goff, stats1, SPLIT);
    gnorm_finalize_kernel<64><<<G, 64, 0, stream>>>(stats1, goff, g1w, g1b, g1a, param);
    gnorm_apply_kernel<<<applyGrid, blk, 0, stream>>>(agg, batch, param, hbuf, N);

    // Layer 2
    gemm2_kernel<64><<<(N + 63) / 64, blk, 0, stream>>>(hbuf, Wl2, Wr2, xl, xr, N);
    agg64_kernel<<<aggGrid, blk, 0, stream>>>(xl, xr, rowstart, csr, att2, b2, agg, N);
    gnorm_stats_kernel<64><<<G * SPLIT, blk, 0, stream>>>(agg, goff, stats2, SPLIT);
    gnorm_finalize_kernel<64><<<G, 64, 0, stream>>>(stats2, goff, g2w, g2b, g2a, param);
    gnorm_apply_kernel<<<applyGrid, blk, 0, stream>>>(agg, batch, param, hbuf, N);

    // Layer 3
    gemm2_kernel<128><<<(N + 31) / 32, blk, 0, stream>>>(hbuf, Wl3, Wr3, xl, xr, N);
    agg128_mean_kernel<<<aggGrid, blk, 0, stream>>>(xl, xr, rowstart, csr, att3, b3, agg, N);
    gnorm_stats_kernel<32><<<G * SPLIT, blk, 0, stream>>>(agg, goff, stats3, SPLIT);
    gnorm_finalize_kernel<32><<<G, 32, 0, stream>>>(stats3, goff, g3w, g3b, g3a, param);
    pool3_kernel<<<G * SPLIT, blk, 0, stream>>>(agg, goff, param, pooled, SPLIT);
    lin_kernel<<<(G * 2 + 63) / 64, 64, 0, stream>>>(pooled, goff, Wlin, blin, outp, G);
}

// Round 3
// 750.765 us; speedup vs baseline: 1.7484x; 1.0412x over previous
//
#include <hip/hip_runtime.h>
#include <hip/hip_bf16.h>

#define LEAKY 0.2f
#define EPS_GN 1e-5f
#define NEG_BIG -3.0e38f

typedef unsigned int uint;

// ---------------- bf16 helpers (storage only; compute fp32) ----------------

__device__ inline float4 bf4(uint2 u) {
    union { uint u; float f; } a, b, c, d;
    a.u = u.x << 16; b.u = u.x & 0xFFFF0000u;
    c.u = u.y << 16; d.u = u.y & 0xFFFF0000u;
    return make_float4(a.f, b.f, c.f, d.f);
}

__device__ inline uint pack_bf2(float lo, float hi) {
    union { float f; uint u; } x, y; x.f = lo; y.f = hi;
    uint ra = x.u + 0x7FFFu + ((x.u >> 16) & 1u);
    uint rb = y.u + 0x7FFFu + ((y.u >> 16) & 1u);
    return (ra >> 16) | (rb & 0xFFFF0000u);
}

// ---------------- CSR build ----------------

__global__ void zero_int_kernel(int* __restrict__ p, int n) {
    int i = blockIdx.x * blockDim.x + threadIdx.x;
    if (i < n) p[i] = 0;
}

__global__ void hist_kernel(const int* __restrict__ dst, int* __restrict__ deg, int E_, int Etot_) {
    int i = blockIdx.x * blockDim.x + threadIdx.x;
    if (i >= Etot_) return;
    int d = (i < E_) ? dst[i] : (i - E_);
    atomicAdd(&deg[d], 1);
}

__global__ void scan1_kernel(const int* __restrict__ deg, int* __restrict__ bsum, int nN) {
    __shared__ int sd[256];
    int i = blockIdx.x * 256 + threadIdx.x;
    sd[threadIdx.x] = (i < nN) ? deg[i] : 0;
    __syncthreads();
    for (int off = 128; off > 0; off >>= 1) {
        if (threadIdx.x < off) sd[threadIdx.x] += sd[threadIdx.x + off];
        __syncthreads();
    }
    if (threadIdx.x == 0) bsum[blockIdx.x] = sd[0];
}

__global__ void scan2_kernel(const int* __restrict__ bsum, int* __restrict__ bofs, int nb,
                             int* __restrict__ rowstart, int nN) {
    if (threadIdx.x == 0 && blockIdx.x == 0) {
        int run = 0;
        for (int i = 0; i < nb; ++i) { bofs[i] = run; run += bsum[i]; }
        rowstart[nN] = run;
    }
}

__global__ void scan3_kernel(const int* __restrict__ deg, const int* __restrict__ bofs,
                             int* __restrict__ rowstart, int nN) {
    __shared__ int sd[256];
    int i = blockIdx.x * 256 + threadIdx.x;
    int v = (i < nN) ? deg[i] : 0;
    sd[threadIdx.x] = v;
    __syncthreads();
    for (int off = 1; off < 256; off <<= 1) {
        int t = (threadIdx.x >= off) ? sd[threadIdx.x - off] : 0;
        __syncthreads();
        sd[threadIdx.x] += t;
        __syncthreads();
    }
    if (i < nN) rowstart[i] = bofs[blockIdx.x] + sd[threadIdx.x] - v;
}

__global__ void fill_kernel(const int* __restrict__ srcs, const int* __restrict__ dsts,
                            const int* __restrict__ rowstart, int* __restrict__ cursor,
                            int* __restrict__ csr, int E_, int Etot_) {
    int i = blockIdx.x * blockDim.x + threadIdx.x;
    if (i >= Etot_) return;
    int s, d;
    if (i < E_) { s = srcs[i]; d = dsts[i]; } else { s = i - E_; d = s; }
    int pos = rowstart[d] + atomicAdd(&cursor[d], 1);
    csr[pos] = s;
}

__global__ void goff_kernel(const int* __restrict__ batch, int* __restrict__ goff, int nN, int nG) {
    int g = blockIdx.x * blockDim.x + threadIdx.x;
    if (g > nG) return;
    if (g == nG) { goff[g] = nN; return; }
    int lo = 0, hi = nN;
    while (lo < hi) { int mid = (lo + hi) >> 1; if (batch[mid] < g) lo = mid + 1; else hi = mid; }
    goff[g] = lo;
}

// ---------------- GEMM: xl = f(x)@Wl, xr = f(x)@Wr (K=64), bf16 out ----------------
// NORM: apply per-graph scale/shift + relu while staging x into LDS.

template <int D, bool NORM>
__global__ void gemm2_kernel(const float* __restrict__ x, const float* __restrict__ Wl,
                             const float* __restrict__ Wr, unsigned short* __restrict__ xl,
                             unsigned short* __restrict__ xr, int nN,
                             const float* __restrict__ param, const int* __restrict__ batch) {
    constexpr int TPN = D / 16;
    constexpr int NPB = 256 / TPN;
    __shared__ float w_s[64 * D];
    __shared__ float x_s[NPB][65];
    int tid = threadIdx.x;
    int node0 = blockIdx.x * NPB;
    for (int i = tid; i < NPB * 64; i += 256) {
        int r = i >> 6, c = i & 63;
        int n = node0 + r;
        float v = 0.f;
        if (n < nN) {
            v = x[(size_t)n * 64 + c];
            if constexpr (NORM) {
                int g = batch[n];
                float sc = param[(size_t)g * 128 + c];
                float sh = param[(size_t)g * 128 + 64 + c];
                v = fmaxf(fmaf(sc, v, sh), 0.f);
            }
        }
        x_s[r][c] = v;
    }
    int local = tid / TPN, j0 = (tid % TPN) * 16;
    int n = node0 + local;
    float acc[16];

    for (int i = tid; i < 64 * D; i += 256) w_s[i] = Wl[i];
    __syncthreads();
#pragma unroll
    for (int j = 0; j < 16; ++j) acc[j] = 0.f;
    for (int k = 0; k < 64; ++k) {
        float xv = x_s[local][k];
        const float* wrow = &w_s[k * D + j0];
#pragma unroll
        for (int j = 0; j < 16; ++j) acc[j] = fmaf(xv, wrow[j], acc[j]);
    }
    if (n < nN) {
        uint4* dst = (uint4*)(xl + (size_t)n * D + j0);
        dst[0] = make_uint4(pack_bf2(acc[0], acc[1]), pack_bf2(acc[2], acc[3]),
                            pack_bf2(acc[4], acc[5]), pack_bf2(acc[6], acc[7]));
        dst[1] = make_uint4(pack_bf2(acc[8], acc[9]), pack_bf2(acc[10], acc[11]),
                            pack_bf2(acc[12], acc[13]), pack_bf2(acc[14], acc[15]));
    }
    __syncthreads();

    for (int i = tid; i < 64 * D; i += 256) w_s[i] = Wr[i];
    __syncthreads();
#pragma unroll
    for (int j = 0; j < 16; ++j) acc[j] = 0.f;
    for (int k = 0; k < 64; ++k) {
        float xv = x_s[local][k];
        const float* wrow = &w_s[k * D + j0];
#pragma unroll
        for (int j = 0; j < 16; ++j) acc[j] = fmaf(xv, wrow[j], acc[j]);
    }
    if (n < nN) {
        uint4* dst = (uint4*)(xr + (size_t)n * D + j0);
        dst[0] = make_uint4(pack_bf2(acc[0], acc[1]), pack_bf2(acc[2], acc[3]),
                            pack_bf2(acc[4], acc[5]), pack_bf2(acc[6], acc[7]));
        dst[1] = make_uint4(pack_bf2(acc[8], acc[9]), pack_bf2(acc[10], acc[11]),
                            pack_bf2(acc[12], acc[13]), pack_bf2(acc[14], acc[15]));
    }
}

// ---------------- Aggregate layer 1-2: D=64, H=4, C=16, concat ----------------
// 4 bf16 ch/lane (8B gather), 16 lanes/edge, 4 edge substreams/wave.

__global__ void agg64_kernel(const unsigned short* __restrict__ xl, const unsigned short* __restrict__ xr,
                             const int* __restrict__ rowstart, const int* __restrict__ csr,
                             const float* __restrict__ att, const float* __restrict__ bias,
                             float* __restrict__ out, int nN) {
    int wid = (blockIdx.x * blockDim.x + threadIdx.x) >> 6;
    int lane = threadIdx.x & 63;
    if (wid >= nN) return;
    int c4 = lane & 15;
    int sg = lane >> 4;
    const uint2* xl2 = (const uint2*)xl;
    float4 attv = ((const float4*)att)[c4];
    float4 xrv = bf4(((const uint2*)xr)[(size_t)wid * 16 + c4]);
    int rs = rowstart[wid], re = rowstart[wid + 1];
    int nIt = (re - rs + 3) >> 2;
    float mx = -1e30f, den = 0.f;
    float4 acc = make_float4(0.f, 0.f, 0.f, 0.f);
    int i = rs + sg;
    bool v = i < re;
    int ic = v ? i : re - 1;
    int s = csr[ic];
    uint2 xv = xl2[(size_t)s * 16 + c4];
    for (int it = 0; it < nIt; ++it) {
        float4 cur = bf4(xv);
        bool vv = v;
        i += 4;
        v = i < re;
        ic = v ? i : re - 1;
        s = csr[ic];
        float4 mm;
        mm.x = cur.x + xrv.x; mm.y = cur.y + xrv.y;
        mm.z = cur.z + xrv.z; mm.w = cur.w + xrv.w;
        mm.x = fmaxf(mm.x, LEAKY * mm.x);
        mm.y = fmaxf(mm.y, LEAKY * mm.y);
        mm.z = fmaxf(mm.z, LEAKY * mm.z);
        mm.w = fmaxf(mm.w, LEAKY * mm.w);
        float p = mm.x * attv.x;
        p = fmaf(mm.y, attv.y, p);
        p = fmaf(mm.z, attv.z, p);
        p = fmaf(mm.w, attv.w, p);
        p += __shfl_xor(p, 1);
        p += __shfl_xor(p, 2);
        xv = xl2[(size_t)s * 16 + c4];   // prefetch next edge
        if (!vv) p = NEG_BIG;
        float nm = fmaxf(mx, p);
        float sc = __expf(mx - nm);
        float w  = __expf(p - nm);
        den = den * sc + w;
        acc.x = fmaf(acc.x, sc, w * cur.x);
        acc.y = fmaf(acc.y, sc, w * cur.y);
        acc.z = fmaf(acc.z, sc, w * cur.z);
        acc.w = fmaf(acc.w, sc, w * cur.w);
        mx = nm;
    }
#pragma unroll
    for (int off = 16; off <= 32; off <<= 1) {
        float om = __shfl_xor(mx, off);
        float od = __shfl_xor(den, off);
        float ox = __shfl_xor(acc.x, off);
        float oy = __shfl_xor(acc.y, off);
        float oz = __shfl_xor(acc.z, off);
        float ow = __shfl_xor(acc.w, off);
        float nm = fmaxf(mx, om);
        float s1 = __expf(mx - nm), s2 = __expf(om - nm);
        den = den * s1 + od * s2;
        acc.x = acc.x * s1 + ox * s2;
        acc.y = acc.y * s1 + oy * s2;
        acc.z = acc.z * s1 + oz * s2;
        acc.w = acc.w * s1 + ow * s2;
        mx = nm;
    }
    if (lane < 16) {
        float4 bv = ((const float4*)bias)[c4];
        float inv = 1.f / den;
        float4 r;
        r.x = acc.x * inv + bv.x;
        r.y = acc.y * inv + bv.y;
        r.z = acc.z * inv + bv.z;
        r.w = acc.w * inv + bv.w;
        ((float4*)out)[(size_t)wid * 16 + c4] = r;
    }
}

// ---------------- Aggregate layer 3: D=128, H=4, C=32, head-mean ----------------

__global__ void agg128_mean_kernel(const unsigned short* __restrict__ xl, const unsigned short* __restrict__ xr,
                                   const int* __restrict__ rowstart, const int* __restrict__ csr,
                                   const float* __restrict__ att, const float* __restrict__ bias,
                                   float* __restrict__ out, int nN) {
    int wid = (blockIdx.x * blockDim.x + threadIdx.x) >> 6;
    int lane = threadIdx.x & 63;
    if (wid >= nN) return;
    int c4 = lane & 31;
    int sg = lane >> 5;
    const uint2* xl2 = (const uint2*)xl;
    float4 attv = ((const float4*)att)[c4];
    float4 xrv = bf4(((const uint2*)xr)[(size_t)wid * 32 + c4]);
    int rs = rowstart[wid], re = rowstart[wid + 1];
    int nIt = (re - rs + 1) >> 1;
    float mx = -1e30f, den = 0.f;
    float4 acc = make_float4(0.f, 0.f, 0.f, 0.f);
    int i = rs + sg;
    bool v = i < re;
    int ic = v ? i : re - 1;
    int s = csr[ic];
    uint2 xv = xl2[(size_t)s * 32 + c4];
    for (int it = 0; it < nIt; ++it) {
        float4 cur = bf4(xv);
        bool vv = v;
        i += 2;
        v = i < re;
        ic = v ? i : re - 1;
        s = csr[ic];
        float4 mm;
        mm.x = cur.x + xrv.x; mm.y = cur.y + xrv.y;
        mm.z = cur.z + xrv.z; mm.w = cur.w + xrv.w;
        mm.x = fmaxf(mm.x, LEAKY * mm.x);
        mm.y = fmaxf(mm.y, LEAKY * mm.y);
        mm.z = fmaxf(mm.z, LEAKY * mm.z);
        mm.w = fmaxf(mm.w, LEAKY * mm.w);
        float p = mm.x * attv.x;
        p = fmaf(mm.y, attv.y, p);
        p = fmaf(mm.z, attv.z, p);
        p = fmaf(mm.w, attv.w, p);
        p += __shfl_xor(p, 1);
        p += __shfl_xor(p, 2);
        p += __shfl_xor(p, 4);
        xv = xl2[(size_t)s * 32 + c4];   // prefetch next edge
        if (!vv) p = NEG_BIG;
        float nm = fmaxf(mx, p);
        float sc = __expf(mx - nm);
        float w  = __expf(p - nm);
        den = den * sc + w;
        acc.x = fmaf(acc.x, sc, w * cur.x);
        acc.y = fmaf(acc.y, sc, w * cur.y);
        acc.z = fmaf(acc.z, sc, w * cur.z);
        acc.w = fmaf(acc.w, sc, w * cur.w);
        mx = nm;
    }
    {
        int off = 32;
        float om = __shfl_xor(mx, off);
        float od = __shfl_xor(den, off);
        float ox = __shfl_xor(acc.x, off);
        float oy = __shfl_xor(acc.y, off);
        float oz = __shfl_xor(acc.z, off);
        float ow = __shfl_xor(acc.w, off);
        float nm = fmaxf(mx, om);
        float s1 = __expf(mx - nm), s2 = __expf(om - nm);
        den = den * s1 + od * s2;
        acc.x = acc.x * s1 + ox * s2;
        acc.y = acc.y * s1 + oy * s2;
        acc.z = acc.z * s1 + oz * s2;
        acc.w = acc.w * s1 + ow * s2;
        mx = nm;
    }
    float inv = 1.f / den;
    float4 r;
    r.x = acc.x * inv; r.y = acc.y * inv; r.z = acc.z * inv; r.w = acc.w * inv;
    r.x += __shfl_xor(r.x, 8);  r.y += __shfl_xor(r.y, 8);
    r.z += __shfl_xor(r.z, 8);  r.w += __shfl_xor(r.w, 8);
    r.x += __shfl_xor(r.x, 16); r.y += __shfl_xor(r.y, 16);
    r.z += __shfl_xor(r.z, 16); r.w += __shfl_xor(r.w, 16);
    if (lane < 8) {
        float4 bv = ((const float4*)bias)[lane];
        float4 o;
        o.x = r.x * 0.25f + bv.x;
        o.y = r.y * 0.25f + bv.y;
        o.z = r.z * 0.25f + bv.z;
        o.w = r.w * 0.25f + bv.w;
        ((float4*)out)[(size_t)wid * 8 + lane] = o;
    }
}

// ---------------- GraphNorm stats / finalize ----------------

template <int D>
__global__ void gnorm_stats_kernel(const float* __restrict__ in, const int* __restrict__ goff,
                                   float* __restrict__ stats, int SPLIT) {
    int g = blockIdx.x / SPLIT, part = blockIdx.x % SPLIT;
    int start = goff[g], end = goff[g + 1];
    constexpr int RPB = 256 / D;
    int tid = threadIdx.x;
    int c = tid % D, sub = tid / D;
    float s1 = 0.f, s2 = 0.f;
    for (int n = start + part * RPB + sub; n < end; n += SPLIT * RPB) {
        float v = in[(size_t)n * D + c];
        s1 += v; s2 += v * v;
    }
    __shared__ float l1[256], l2[256];
    l1[tid] = s1; l2[tid] = s2;
    __syncthreads();
    if (tid < D) {
        for (int s = 1; s < RPB; ++s) { s1 += l1[s * D + tid]; s2 += l2[s * D + tid]; }
        atomicAdd(&stats[(size_t)g * 2 * D + tid], s1);
        atomicAdd(&stats[(size_t)g * 2 * D + D + tid], s2);
    }
}

template <int D>
__global__ void gnorm_finalize_kernel(const float* __restrict__ stats, const int* __restrict__ goff,
                                      const float* __restrict__ w, const float* __restrict__ b,
                                      const float* __restrict__ a, float* __restrict__ param) {
    int g = blockIdx.x, c = threadIdx.x;
    if (c >= D) return;
    int cn = goff[g + 1] - goff[g];
    float cnt = (float)(cn > 1 ? cn : 1);
    float S1 = stats[(size_t)g * 2 * D + c], S2 = stats[(size_t)g * 2 * D + D + c];
    float mu = S1 / cnt;
    float am = a[c] * mu;
    float var = S2 / cnt - 2.f * am * mu + am * am;
    float sc = w[c] * rsqrtf(var + EPS_GN);
    param[(size_t)g * 2 * D + c] = sc;
    param[(size_t)g * 2 * D + D + c] = b[c] - sc * am;
}

// ---------------- layer-3 tail ----------------

__global__ void pool3_kernel(const float* __restrict__ in, const int* __restrict__ goff,
                             const float* __restrict__ param, float* __restrict__ pooled, int SPLIT) {
    int g = blockIdx.x / SPLIT, part = blockIdx.x % SPLIT;
    int start = goff[g], end = goff[g + 1];
    int tid = threadIdx.x;
    int c = tid & 31, sub = tid >> 5;
    float sc = param[(size_t)g * 64 + c], sh = param[(size_t)g * 64 + 32 + c];
    float s = 0.f;
    for (int n = start + part * 8 + sub; n < end; n += SPLIT * 8)
        s += fmaxf(fmaf(sc, in[(size_t)n * 32 + c], sh), 0.f);
    __shared__ float l[256];
    l[tid] = s;
    __syncthreads();
    if (tid < 32) {
        for (int q = 1; q < 8; ++q) s += l[q * 32 + tid];
        atomicAdd(&pooled[(size_t)g * 32 + tid], s);
    }
}

__global__ void lin_kernel(const float* __restrict__ pooled, const int* __restrict__ goff,
                           const float* __restrict__ Wlin, const float* __restrict__ blin,
                           float* __restrict__ out, int nG) {
    int idx = blockIdx.x * blockDim.x + threadIdx.x;
    if (idx >= nG * 2) return;
    int g = idx >> 1, o = idx & 1;
    int cn = goff[g + 1] - goff[g];
    float inv = 1.f / (float)(cn > 1 ? cn : 1);
    float acc = blin[o];
    for (int c = 0; c < 32; ++c) acc = fmaf(pooled[(size_t)g * 32 + c] * inv, Wlin[c * 2 + o], acc);
    out[idx] = acc;
}

// ---------------- launch ----------------

extern "C" void kernel_launch(void* const* d_in, const int* in_sizes, int n_in,
                              void* d_out, int out_size, void* d_ws, size_t ws_size,
                              hipStream_t stream) {
    const float* x    = (const float*)d_in[0];
    const int*  eidx  = (const int*)d_in[1];
    const int*  batch = (const int*)d_in[2];
    const float* Wl1 = (const float*)d_in[3];
    const float* Wr1 = (const float*)d_in[4];
    const float* att1 = (const float*)d_in[5];
    const float* b1 = (const float*)d_in[6];
    const float* g1w = (const float*)d_in[7];
    const float* g1b = (const float*)d_in[8];
    const float* g1a = (const float*)d_in[9];
    const float* Wl2 = (const float*)d_in[10];
    const float* Wr2 = (const float*)d_in[11];
    const float* att2 = (const float*)d_in[12];
    const float* b2 = (const float*)d_in[13];
    const float* g2w = (const float*)d_in[14];
    const float* g2b = (const float*)d_in[15];
    const float* g2a = (const float*)d_in[16];
    const float* Wl3 = (const float*)d_in[17];
    const float* Wr3 = (const float*)d_in[18];
    const float* att3 = (const float*)d_in[19];
    const float* b3 = (const float*)d_in[20];
    const float* g3w = (const float*)d_in[21];
    const float* g3b = (const float*)d_in[22];
    const float* g3a = (const float*)d_in[23];
    const float* Wlin = (const float*)d_in[24];
    const float* blin = (const float*)d_in[25];
    float* outp = (float*)d_out;

    const int N = in_sizes[0] / 64;
    const int E = in_sizes[1] / 2;
    const int Etot = N + E;
    const int G = out_size / 2;
    const int NB = (N + 255) / 256;
    const int SPLIT = 16;

    unsigned short* xlb = (unsigned short*)d_ws;           // N*128 bf16
    unsigned short* xrb = xlb + (size_t)N * 128;           // N*128 bf16
    float* agg   = (float*)(xrb + (size_t)N * 128);        // N*64 f32
    float* stats = agg + (size_t)N * 64;
    float* stats1 = stats;
    float* stats2 = stats1 + (size_t)G * 128;
    float* stats3 = stats2 + (size_t)G * 128;
    float* pooled = stats3 + (size_t)G * 64;
    float* param  = pooled + (size_t)G * 32;               // G*128, reused per layer
    int* deg      = (int*)(param + (size_t)G * 128);
    int* cursor   = deg + N;
    int* rowstart = cursor + N;
    int* csr      = rowstart + (N + 1);
    int* bsum     = csr + Etot;
    int* bofs     = bsum + NB;
    int* goff     = bofs + NB;

    const int* src_idx = eidx;
    const int* dst_idx = eidx + E;

    zero_int_kernel<<<(2 * N + 255) / 256, 256, 0, stream>>>(deg, 2 * N);
    zero_int_kernel<<<(G * 352 + 255) / 256, 256, 0, stream>>>((int*)stats, G * 352);

    hist_kernel<<<(Etot + 255) / 256, 256, 0, stream>>>(dst_idx, deg, E, Etot);
    scan1_kernel<<<NB, 256, 0, stream>>>(deg, bsum, N);
    scan2_kernel<<<1, 64, 0, stream>>>(bsum, bofs, NB, rowstart, N);
    scan3_kernel<<<NB, 256, 0, stream>>>(deg, bofs, rowstart, N);
    fill_kernel<<<(Etot + 255) / 256, 256, 0, stream>>>(src_idx, dst_idx, rowstart, cursor, csr, E, Etot);
    goff_kernel<<<1, 128, 0, stream>>>(batch, goff, N, G);

    dim3 blk(256);
    int aggGrid = (N + 3) / 4;

    // Layer 1
    gemm2_kernel<64, false><<<(N + 63) / 64, blk, 0, stream>>>(x, Wl1, Wr1, xlb, xrb, N, nullptr, nullptr);
    agg64_kernel<<<aggGrid, blk, 0, stream>>>(xlb, xrb, rowstart, csr, att1, b1, agg, N);
    gnorm_stats_kernel<64><<<G * SPLIT, blk, 0, stream>>>(agg, goff, stats1, SPLIT);
    gnorm_finalize_kernel<64><<<G, 64, 0, stream>>>(stats1, goff, g1w, g1b, g1a, param);

    // Layer 2 (norm of layer 1 fused into GEMM staging)
    gemm2_kernel<64, true><<<(N + 63) / 64, blk, 0, stream>>>(agg, Wl2, Wr2, xlb, xrb, N, param, batch);
    agg64_kernel<<<aggGrid, blk, 0, stream>>>(xlb, xrb, rowstart, csr, att2, b2, agg, N);
    gnorm_stats_kernel<64><<<G * SPLIT, blk, 0, stream>>>(agg, goff, stats2, SPLIT);
    gnorm_finalize_kernel<64><<<G, 64, 0, stream>>>(stats2, goff, g2w, g2b, g2a, param);

    // Layer 3 (norm of layer 2 fused into GEMM staging)
    gemm2_kernel<128, true><<<(N + 31) / 32, blk, 0, stream>>>(agg, Wl3, Wr3, xlb, xrb, N, param, batch);
    agg128_mean_kernel<<<aggGrid, blk, 0, stream>>>(xlb, xrb, rowstart, csr, att3, b3, agg, N);
    gnorm_stats_kernel<32><<<G * SPLIT, blk, 0, stream>>>(agg, goff, stats3, SPLIT);
    gnorm_finalize_kernel<32><<<G, 32, 0, stream>>>(stats3, goff, g3w, g3b, g3a, param);
    pool3_kernel<<<G * SPLIT, blk, 0, stream>>>(agg, goff, param, pooled, SPLIT);
    lin_kernel<<<(G * 2 + 63) / 64, 64, 0, stream>>>(pooled, goff, Wlin, blin, outp, G);
}